// Round 7
// baseline (44.238 us; speedup 1.0000x reference)
//
#include <hip/hip_runtime.h>

typedef __bf16 bf16x8 __attribute__((ext_vector_type(8)));
typedef float f32x16 __attribute__((ext_vector_type(16)));
typedef float f32x4  __attribute__((ext_vector_type(4)));
typedef unsigned int u32x2 __attribute__((ext_vector_type(2)));
typedef unsigned int u32x4 __attribute__((ext_vector_type(4)));

#define HEAD_DIM 128
#define D_MODEL  4096   // 32 heads * 128

// pack two floats into one u32 of 2x bf16 (RNE via __bf16 cast)
__device__ __forceinline__ unsigned pack_bf16(float lo, float hi) {
    unsigned a = (unsigned)__builtin_bit_cast(unsigned short, (__bf16)lo);
    unsigned b = (unsigned)__builtin_bit_cast(unsigned short, (__bf16)hi);
    return a | (b << 16);
}

// ONE WAVE PER BLOCK, one block per batch row b. launch_bounds(64,2) lifts
// the VGPR cap to 256 so ALL of this wave's loads (V 64 + Q 64 + K 64 regs,
// 48KB) are issued back-to-back with no intra-wave vmcnt drain bubbles.
// Issue order V -> Q -> K: Q-convert waits at vmcnt(16) (K outstanding),
// K-convert at vmcnt(0) (V returned long before; in-order counting).
// Occupancy: VGPR-bound ~8 waves/CU (LDS would allow 10) — each an
// independent de-phased workgroup, no barriers (same-wave LDS coherence).
//   scores^T = mfma(A=K, B=Q) -> D[kv][h]: lane holds h = lane&31,
//   kv(reg) = (reg&3) + 8*(reg>>2) + 4*(lane>>5)
__global__ __launch_bounds__(64, 2) void attn_kernel(
    const float* __restrict__ q,
    const float* __restrict__ k,
    const float* __restrict__ v,
    float* __restrict__ out)
{
    constexpr float SCALE_LOG2E = 0.08838834764831845f * 1.4426950408889634f;

    __shared__ char lds[16384];     // Q bf16 8KB + K bf16 8KB
    char* ldsQ = lds;
    char* ldsK = lds + 8192;

    const int lane = threadIdx.x;   // 0..63
    const int b  = blockIdx.x;
    const int r  = lane & 31;
    const int hi = lane >> 5;

    const float* qb = q + (size_t)b * D_MODEL;
    const float* kb = k + (size_t)b * D_MODEL;
    const float* vb = v + (size_t)b * D_MODEL;

    // ---- 1. issue ALL loads back-to-back: V, then Q, then K ----
    // V: vf[t*32 + c*8 + j] = V[t*16 + hi*8 + j][c*32 + r]  (full 128B lines)
    float vf[64];
#pragma unroll
    for (int t = 0; t < 2; ++t)
#pragma unroll
        for (int c = 0; c < 4; ++c) {
            const float* vp = vb + (size_t)(t * 16 + hi * 8) * HEAD_DIM + c * 32 + r;
#pragma unroll
            for (int j = 0; j < 8; ++j)
                vf[t * 32 + c * 8 + j] = vp[(size_t)j * HEAD_DIM];
        }

    // Q, K: contiguous dwordx4 (1KB/instr, full-line requests)
    f32x4 qraw[16], kraw[16];
#pragma unroll
    for (int i = 0; i < 16; ++i)
        qraw[i] = *(const f32x4*)(qb + i * 256 + lane * 4);
#pragma unroll
    for (int i = 0; i < 16; ++i)
        kraw[i] = *(const f32x4*)(kb + i * 256 + lane * 4);

    // ---- 2. Q -> bf16 -> LDS (XOR row-swizzle) ----
#pragma unroll
    for (int i = 0; i < 16; ++i) {
        const int byteoff = i * 512 + lane * 8;
        const int row = byteoff >> 8;
        const int swz = byteoff ^ ((row & 7) << 4);
        u32x2 w2;
        w2[0] = pack_bf16(qraw[i][0], qraw[i][1]);
        w2[1] = pack_bf16(qraw[i][2], qraw[i][3]);
        *(u32x2*)(ldsQ + swz) = w2;
    }

    // ---- 3. K -> bf16 -> LDS ----
#pragma unroll
    for (int i = 0; i < 16; ++i) {
        const int byteoff = i * 512 + lane * 8;
        const int row = byteoff >> 8;
        const int swz = byteoff ^ ((row & 7) << 4);
        u32x2 w2;
        w2[0] = pack_bf16(kraw[i][0], kraw[i][1]);
        w2[1] = pack_bf16(kraw[i][2], kraw[i][3]);
        *(u32x2*)(ldsK + swz) = w2;
    }

    // ---- 4. QK^T MFMA chain from LDS fragments ----
    f32x16 acc = {};
#pragma unroll
    for (int s = 0; s < 8; ++s) {
        const int fb   = r * 256 + s * 32 + hi * 16;
        const int fswz = fb ^ ((r & 7) << 4);
        bf16x8 aK = *(const bf16x8*)(ldsK + fswz);
        bf16x8 bQ = *(const bf16x8*)(ldsQ + fswz);
        acc = __builtin_amdgcn_mfma_f32_32x32x16_bf16(aK, bQ, acc, 0, 0, 0);
    }

    // ---- 5. softmax over kv (h = r is lane-local), in place ----
    float m = acc[0];
#pragma unroll
    for (int i = 1; i < 16; ++i) m = fmaxf(m, acc[i]);
    m = fmaxf(m, __shfl_xor(m, 32, 64));

    float sum = 0.f;
#pragma unroll
    for (int i = 0; i < 16; ++i) {
        acc[i] = __builtin_amdgcn_exp2f((acc[i] - m) * SCALE_LOG2E);
        sum += acc[i];
    }
    sum += __shfl_xor(sum, 32, 64);
    const float inv = __builtin_amdgcn_rcpf(sum);

    // ---- 6. repack into A-fragment of P^T[h][kv] ----
    unsigned w[8];
#pragma unroll
    for (int i = 0; i < 8; ++i) w[i] = pack_bf16(acc[2 * i] * inv, acc[2 * i + 1] * inv);

    bf16x8 pa[2];
#pragma unroll
    for (int t = 0; t < 2; ++t) {
        unsigned W0 = w[4 * t], W1 = w[4 * t + 1], W2 = w[4 * t + 2], W3 = w[4 * t + 3];
        unsigned X0 = (unsigned)__shfl_xor((int)W0, 32, 64);
        unsigned X1 = (unsigned)__shfl_xor((int)W1, 32, 64);
        unsigned X2 = (unsigned)__shfl_xor((int)W2, 32, 64);
        unsigned X3 = (unsigned)__shfl_xor((int)W3, 32, 64);
        u32x4 wv;
        wv[0] = hi ? X2 : W0;
        wv[1] = hi ? X3 : W1;
        wv[2] = hi ? W2 : X0;
        wv[3] = hi ? W3 : X1;
        pa[t] = __builtin_bit_cast(bf16x8, wv);
    }

    // ---- 7. out[h][d] = P^T * V ----
    float* ob = out + (size_t)b * D_MODEL;
#pragma unroll
    for (int c = 0; c < 4; ++c) {
        f32x16 oacc = {};
#pragma unroll
        for (int t = 0; t < 2; ++t) {
            bf16x8 bV;
#pragma unroll
            for (int j = 0; j < 8; ++j) bV[j] = (__bf16)vf[t * 32 + c * 8 + j];
            oacc = __builtin_amdgcn_mfma_f32_32x32x16_bf16(pa[t], bV, oacc, 0, 0, 0);
        }
        float* op = ob + c * 32 + r;
#pragma unroll
        for (int reg = 0; reg < 16; ++reg) {
            const int h = (reg & 3) + 8 * (reg >> 2) + 4 * hi;
            op[(size_t)h * HEAD_DIM] = oacc[reg];
        }
    }
}

extern "C" void kernel_launch(void* const* d_in, const int* in_sizes, int n_in,
                              void* d_out, int out_size, void* d_ws, size_t ws_size,
                              hipStream_t stream) {
    const float* q = (const float*)d_in[0];
    const float* k = (const float*)d_in[1];
    const float* v = (const float*)d_in[2];
    float* out = (float*)d_out;
    const int B = in_sizes[0] / D_MODEL;   // 4096
    attn_kernel<<<dim3(B), dim3(64), 0, stream>>>(q, k, v, out);
}